// Round 4
// baseline (1639.418 us; speedup 1.0000x reference)
//
#include <hip/hip_runtime.h>

#define NQ 273
#define NB 2

typedef float f4 __attribute__((ext_vector_type(4)));

// ---------------- compile-time GA tables (Cl(3,0,1) PGA, 16 blades) ----------------
struct GATab {
  int qi[NQ]; int qj[NQ]; int qk[NQ];
  float qs[NQ];
  int qgp[NQ];
  int qpath[NQ];
  int ngp, njp, nq;
};

constexpr int popc4(int m){ int c=0; for(int b=0;b<5;++b) c+=(m>>b)&1; return c; }
constexpr int swap_par(int a,int b){ int s=0; a>>=1; while(a){ s+=popc4(a&b); a>>=1; } return s&1; }

constexpr GATab make_tab(){
  GATab t{};
  int bladeOf[16]={}; int idxOf[16]={};
  { int p=0;
    for(int g=0; g<=4; ++g)
      for(int m=0; m<16; ++m)
        if(popc4(m)==g){ bladeOf[p]=m; idxOf[m]=p; ++p; }
  }
  int grade[16]={};
  for(int j=0;j<16;++j) grade[j]=popc4(bladeOf[j]);
  bool gpp[125]={}; bool jpp[125]={};
  for(int j=0;j<16;++j) for(int k=0;k<16;++k){
    int mj=bladeOf[j], mk=bladeOf[k];
    if(!(mj&mk&1)){ int i=idxOf[mj^mk]; gpp[(grade[i]*5+grade[j])*5+grade[k]]=true; }
    int cj=15^mj, ck=15^mk;
    if(!(cj&ck)){ int r=mj&mk; int i=idxOf[r]; jpp[(grade[i]*5+grade[j])*5+grade[k]]=true; }
  }
  int gpidx[125]={}; int jpidx[125]={};
  { int c=0; for(int u=0;u<125;++u){ gpidx[u] = gpp[u]? c++ : -1; } t.ngp=c; }
  { int c=0; for(int u=0;u<125;++u){ jpidx[u] = jpp[u]? c++ : -1; } t.njp=c; }
  int q=0;
  for(int j=0;j<16;++j) for(int k=0;k<16;++k){
    int mj=bladeOf[j], mk=bladeOf[k];
    if(!(mj&mk&1)){
      int i=idxOf[mj^mk];
      t.qi[q]=i; t.qj[q]=j; t.qk[q]=k;
      t.qs[q] = swap_par(mj,mk) ? -1.0f : 1.0f;
      t.qgp[q]=1;
      t.qpath[q]=gpidx[(grade[i]*5+grade[j])*5+grade[k]];
      ++q;
    }
  }
  for(int j=0;j<16;++j) for(int k=0;k<16;++k){
    int mj=bladeOf[j], mk=bladeOf[k];
    int cj=15^mj, ck=15^mk;
    if(!(cj&ck)){
      int r=mj&mk; int i=idxOf[r];
      int par = swap_par(mj,15^mj) ^ swap_par(mk,15^mk) ^ swap_par(cj,ck) ^ swap_par(r,15^r);
      t.qi[q]=i; t.qj[q]=j; t.qk[q]=k;
      t.qs[q] = par ? -1.0f : 1.0f;
      t.qgp[q]=0;
      t.qpath[q]=jpidx[(grade[i]*5+grade[j])*5+grade[k]];
      ++q;
    }
  }
  t.nq=q;
  return t;
}

constexpr GATab TAB = make_tab();
static_assert(TAB.nq == NQ, "nonzero count mismatch");
static_assert(TAB.ngp > 0 && TAB.njp > 0, "path counts");
constexpr int NGPC = TAB.ngp;
constexpr int NJPC = TAB.njp;
constexpr int GR[16] = {0,1,1,1,1,2,2,2,2,2,2,3,3,3,3,4};

__device__ __forceinline__ float rdlane(float v, int i){
  return __uint_as_float((unsigned)__builtin_amdgcn_readlane((int)__float_as_uint(v), i));
}

// ---------------- prep kernels ----------------
// repack lin_weight (128,64,5) -> wls_g[i][s][n], s in [0,10):
//   s in [0,5):  w1 grade s for output channel n      (o = n)
//   s in [5,10): w2 grade s-5 for output channel n+64 (o = 64+n)
// 64*10*64 floats = 160 KB; stride-1 in n -> conflict-free ds_read_b32 in main_k.
__global__ void prep_wls(const float* __restrict__ linw, float* __restrict__ wls_g){
  int t = blockIdx.x*blockDim.x + threadIdx.x;
  if(t < 64*10*64){
    int n = t & 63;
    int s = (t >> 6) % 10;
    int i = t / 640;
    float v;
    if(s < 5) v = linw[(n*64 + i)*5 + s];
    else      v = linw[((64+n)*64 + i)*5 + (s-5)];
    wls_g[t] = v;
  }
}

// coef[q][n] = sign_q * (gp? gpw[n][path] : jpw[n][path]);  fully unrolled -> TAB folds
__global__ void prep_coef(const float* __restrict__ gpw, const float* __restrict__ jpw,
                          float* __restrict__ coef){
  int n = threadIdx.x; // blockDim = 64, grid = 1
  #pragma unroll
  for(int q=0;q<NQ;++q){
    float w = TAB.qgp[q] ? gpw[n*NGPC + TAB.qpath[q]] : jpw[n*NJPC + TAB.qpath[q]];
    coef[q*64 + n] = TAB.qs[q]*w;
  }
}

// ---------------- main fused kernel ----------------
// Data path redesign:
//  - Weight table (160 KB) lives in LDS, staged once per block; read as
//    conflict-free ds_read_b32 ([i][s][n], stride-1 in lane n).
//  - x is wave-uniform per (i,v): lane l loads x[b][l][0..15] into VGPRs, then
//    v_readlane broadcasts lane i's values to SGPRs (no LDS broadcast bus cost,
//    no per-wave 192KB/pass weight re-stream from L2).
//  - 512-thread block (8 waves), 1 block/CU (LDS-bound), 2 waves/SIMD.
__global__ __launch_bounds__(512)
void main_k(const float* __restrict__ x, const float* __restrict__ coef,
            const float* __restrict__ wls_g, float* __restrict__ out, int B){
  __shared__ float wls[64*10*64];   // 160 KB exactly

  const int tid  = threadIdx.x;
  const int lane = tid & 63;
  const int wv   = tid >> 6;        // 0..7
  const int n    = lane;

  // ---- stage weight table once per block: 10240 f4 / 512 thr = 20 each ----
  {
    const f4* src = (const f4*)wls_g;
    f4* dst = (f4*)wls;
    #pragma unroll
    for(int k=0;k<20;++k) dst[tid + k*512] = src[tid + k*512];
  }
  __syncthreads();

  const float* cp = coef + n;

  for(int base = blockIdx.x*(8*NB); base < B; base += gridDim.x*(8*NB)){
    const int b0 = base + wv*NB;

    // ---- load this wave's NB batch elements into registers (lane = channel) ----
    f4 xr[NB][4];
    #pragma unroll
    for(int t=0;t<NB;++t){
      int bb = b0 + t;
      if(bb < B){
        const f4* src = (const f4*)(x + ((long)bb*64 + lane)*16);
        #pragma unroll
        for(int r=0;r<4;++r) xr[t][r] = __builtin_nontemporal_load(src+r);
      }
    }

    // ---- linear phase: y1[v] = sum_i w1[g(v)]*x[i][v], y2 likewise ----
    float y1[NB][16]; float y2[NB][16];
    #pragma unroll
    for(int t=0;t<NB;++t)
      #pragma unroll
      for(int v=0;v<16;++v){ y1[t][v]=0.f; y2[t][v]=0.f; }

    #pragma unroll 2
    for(int i=0;i<64;++i){
      float w1[5], w2[5];
      #pragma unroll
      for(int g=0;g<5;++g){
        w1[g] = wls[(i*10+g)*64 + n];
        w2[g] = wls[(i*10+5+g)*64 + n];
      }
      #pragma unroll
      for(int t=0;t<NB;++t){
        #pragma unroll
        for(int v=0;v<16;++v){
          float xv = rdlane(xr[t][v>>2][v&3], i);   // x[b0+t][i][v], uniform (SGPR)
          y1[t][v] = fmaf(w1[GR[v]], xv, y1[t][v]);
          y2[t][v] = fmaf(w2[GR[v]], xv, y2[t][v]);
        }
      }
    }

    // ---- bilinear phase: acc[i] = y2[i] + sum_q coef[n,q]*y1[j_q]*y2[k_q] ----
    float acc[NB][16];
    #pragma unroll
    for(int t=0;t<NB;++t)
      #pragma unroll
      for(int v=0;v<16;++v) acc[t][v]=y2[t][v];

    #pragma unroll
    for(int q=0;q<NQ;++q){
      float c = cp[q*64];
      #pragma unroll
      for(int t=0;t<NB;++t){
        acc[t][TAB.qi[q]] = fmaf(c, y1[t][TAB.qj[q]]*y2[t][TAB.qk[q]], acc[t][TAB.qi[q]]);
      }
    }

    // ---- store (streamed once -> nontemporal) ----
    #pragma unroll
    for(int t=0;t<NB;++t){
      int bb = b0 + t;
      if(bb < B){
        f4* op = (f4*)(out + ((long)bb*64 + n)*16);
        #pragma unroll
        for(int r=0;r<4;++r){
          f4 o; o[0]=acc[t][4*r]; o[1]=acc[t][4*r+1]; o[2]=acc[t][4*r+2]; o[3]=acc[t][4*r+3];
          __builtin_nontemporal_store(o, op+r);
        }
      }
    }
  }
}

extern "C" void kernel_launch(void* const* d_in, const int* in_sizes, int n_in,
                              void* d_out, int out_size, void* d_ws, size_t ws_size,
                              hipStream_t stream){
  const float* x    = (const float*)d_in[0];
  const float* gpw  = (const float*)d_in[1];
  const float* jpw  = (const float*)d_in[2];
  const float* linw = (const float*)d_in[3];
  float* outp = (float*)d_out;

  float* wls_g = (float*)d_ws;         // 64*10*64 floats = 160 KB
  float* coef  = wls_g + 64*10*64;     // NQ*64 floats ≈ 68 KB

  int B = in_sizes[0] / (64*16);

  prep_wls <<<160, 256, 0, stream>>>(linw, wls_g);
  prep_coef<<<1,   64,  0, stream>>>(gpw, jpw, coef);
  main_k   <<<256, 512, 0, stream>>>(x, coef, wls_g, outp, B);
}

// Round 5
// 818.257 us; speedup vs baseline: 2.0035x; 2.0035x over previous
//
#include <hip/hip_runtime.h>

#define NQ 273

typedef float f4 __attribute__((ext_vector_type(4)));

// ---------------- compile-time GA tables (Cl(3,0,1) PGA, 16 blades) ----------------
struct GATab {
  int qi[NQ]; int qj[NQ]; int qk[NQ];
  float qs[NQ];
  int qgp[NQ];
  int qpath[NQ];
  int ngp, njp, nq;
};

constexpr int popc4(int m){ int c=0; for(int b=0;b<5;++b) c+=(m>>b)&1; return c; }
constexpr int swap_par(int a,int b){ int s=0; a>>=1; while(a){ s+=popc4(a&b); a>>=1; } return s&1; }

constexpr GATab make_tab(){
  GATab t{};
  int bladeOf[16]={}; int idxOf[16]={};
  { int p=0;
    for(int g=0; g<=4; ++g)
      for(int m=0; m<16; ++m)
        if(popc4(m)==g){ bladeOf[p]=m; idxOf[m]=p; ++p; }
  }
  int grade[16]={};
  for(int j=0;j<16;++j) grade[j]=popc4(bladeOf[j]);
  bool gpp[125]={}; bool jpp[125]={};
  for(int j=0;j<16;++j) for(int k=0;k<16;++k){
    int mj=bladeOf[j], mk=bladeOf[k];
    if(!(mj&mk&1)){ int i=idxOf[mj^mk]; gpp[(grade[i]*5+grade[j])*5+grade[k]]=true; }
    int cj=15^mj, ck=15^mk;
    if(!(cj&ck)){ int r=mj&mk; int i=idxOf[r]; jpp[(grade[i]*5+grade[j])*5+grade[k]]=true; }
  }
  int gpidx[125]={}; int jpidx[125]={};
  { int c=0; for(int u=0;u<125;++u){ gpidx[u] = gpp[u]? c++ : -1; } t.ngp=c; }
  { int c=0; for(int u=0;u<125;++u){ jpidx[u] = jpp[u]? c++ : -1; } t.njp=c; }
  int q=0;
  for(int j=0;j<16;++j) for(int k=0;k<16;++k){
    int mj=bladeOf[j], mk=bladeOf[k];
    if(!(mj&mk&1)){
      int i=idxOf[mj^mk];
      t.qi[q]=i; t.qj[q]=j; t.qk[q]=k;
      t.qs[q] = swap_par(mj,mk) ? -1.0f : 1.0f;
      t.qgp[q]=1;
      t.qpath[q]=gpidx[(grade[i]*5+grade[j])*5+grade[k]];
      ++q;
    }
  }
  for(int j=0;j<16;++j) for(int k=0;k<16;++k){
    int mj=bladeOf[j], mk=bladeOf[k];
    int cj=15^mj, ck=15^mk;
    if(!(cj&ck)){
      int r=mj&mk; int i=idxOf[r];
      int par = swap_par(mj,15^mj) ^ swap_par(mk,15^mk) ^ swap_par(cj,ck) ^ swap_par(r,15^r);
      t.qi[q]=i; t.qj[q]=j; t.qk[q]=k;
      t.qs[q] = par ? -1.0f : 1.0f;
      t.qgp[q]=0;
      t.qpath[q]=jpidx[(grade[i]*5+grade[j])*5+grade[k]];
      ++q;
    }
  }
  t.nq=q;
  return t;
}

constexpr GATab TAB = make_tab();
static_assert(TAB.nq == NQ, "nonzero count mismatch");
static_assert(TAB.ngp > 0 && TAB.njp > 0, "path counts");
constexpr int NGPC = TAB.ngp;
constexpr int NJPC = TAB.njp;
constexpr int GR[16] = {0,1,1,1,1,2,2,2,2,2,2,3,3,3,3,4};

__device__ __forceinline__ float rdlane(float v, int i){
  return __uint_as_float((unsigned)__builtin_amdgcn_readlane((int)__float_as_uint(v), i));
}

// ---------------- prep kernels ----------------
// repack lin_weight (128,64,5) -> wrp[i][n][12]:
//   s in [0,5):  w1 grade s for output channel n      (o = n)
//   s in [5,10): w2 grade s-5 for output channel n+64 (o = 64+n)
//   s in [10,12): pad -> 48 B record, 3x dwordx4 per (i,n)
__global__ void prep_wrp(const float* __restrict__ linw, float* __restrict__ wrp){
  int t = blockIdx.x*blockDim.x + threadIdx.x;
  if(t < 64*64*12){
    int s = t % 12;
    int n = (t/12) & 63;
    int i = t/(12*64);
    float v = 0.f;
    if(s < 5)       v = linw[(n*64 + i)*5 + s];
    else if(s < 10) v = linw[((64+n)*64 + i)*5 + (s-5)];
    wrp[t] = v;
  }
}

// coef[q][n] = sign_q * (gp? gpw[n][path] : jpw[n][path]);  fully unrolled -> TAB folds
__global__ void prep_coef(const float* __restrict__ gpw, const float* __restrict__ jpw,
                          float* __restrict__ coef){
  int n = threadIdx.x; // blockDim = 64, grid = 1
  #pragma unroll
  for(int q=0;q<NQ;++q){
    float w = TAB.qgp[q] ? gpw[n*NGPC + TAB.qpath[q]] : jpw[n*NJPC + TAB.qpath[q]];
    coef[q*64 + n] = TAB.qs[q]*w;
  }
}

// ---------------- main fused kernel ----------------
// NB=1, 512-thread blocks. Design:
//  - coef (68 KB) staged in LDS once per block: removes the 273-global-load
//    hoist that spilled R2/R3, and the per-pass coef L2 stream. Stride-1 in
//    lane n -> 0 bank conflicts.
//  - x loaded per-lane (lane = input channel) into 16 VGPRs; lane i's values
//    broadcast via v_readlane (SGPR operand to the FMA) -- no LDS for x.
//  - weights stream from L2 (192 KB table, L2-resident; FETCH stays tiny).
//  - live set ~100 floats < the toolchain's 128-VGPR cap for 512-thr blocks
//    -> zero spill; 68 KB LDS -> 2 blocks/CU -> 16 waves/CU (4/SIMD).
__global__ __launch_bounds__(512)
void main_k(const float* __restrict__ x, const float* __restrict__ coef,
            const float* __restrict__ wrp, float* __restrict__ out, int B){
  __shared__ float cl[NQ*64];   // 68.25 KB

  const int tid  = threadIdx.x;
  const int lane = tid & 63;
  const int wv   = tid >> 6;        // 0..7
  const int n    = lane;

  // ---- stage coef once per block: 4368 f4 / 512 thr = 9 chunks ----
  {
    const f4* src = (const f4*)coef;
    f4* dst = (f4*)cl;
    #pragma unroll
    for(int k=0;k<9;++k){
      int idx = tid + k*512;
      if(idx < NQ*16) dst[idx] = src[idx];
    }
  }
  __syncthreads();

  for(int base = blockIdx.x*8; base < B; base += gridDim.x*8){
    const int bb = base + wv;

    // ---- load this wave's batch element into registers (lane = channel) ----
    f4 xr[4];
    if(bb < B){
      const f4* src = (const f4*)(x + ((long)bb*64 + lane)*16);
      #pragma unroll
      for(int r=0;r<4;++r) xr[r] = __builtin_nontemporal_load(src+r);
    }

    // ---- linear phase: y1[v] = sum_i w1[g(v)]*x[i][v], y2 likewise ----
    float y1[16], y2[16];
    #pragma unroll
    for(int v=0;v<16;++v){ y1[v]=0.f; y2[v]=0.f; }

    #pragma unroll 2
    for(int i=0;i<64;++i){
      const f4* wp = (const f4*)(wrp + (i*64 + n)*12);
      f4 wa = wp[0], wb = wp[1], wc = wp[2];
      float w1[5] = {wa[0],wa[1],wa[2],wa[3],wb[0]};
      float w2[5] = {wb[1],wb[2],wb[3],wc[0],wc[1]};
      #pragma unroll
      for(int v=0;v<16;++v){
        float xv = rdlane(xr[v>>2][v&3], i);   // x[bb][i][v], wave-uniform (SGPR)
        y1[v] = fmaf(w1[GR[v]], xv, y1[v]);
        y2[v] = fmaf(w2[GR[v]], xv, y2[v]);
      }
    }

    // ---- bilinear phase: acc[i] = y2[i] + sum_q coef[n,q]*y1[j_q]*y2[k_q] ----
    float acc[16];
    #pragma unroll
    for(int v=0;v<16;++v) acc[v]=y2[v];

    #pragma unroll
    for(int q=0;q<NQ;++q){
      float c = cl[q*64 + n];
      acc[TAB.qi[q]] = fmaf(c, y1[TAB.qj[q]]*y2[TAB.qk[q]], acc[TAB.qi[q]]);
    }

    // ---- store (streamed once -> nontemporal) ----
    if(bb < B){
      f4* op = (f4*)(out + ((long)bb*64 + n)*16);
      #pragma unroll
      for(int r=0;r<4;++r){
        f4 o; o[0]=acc[4*r]; o[1]=acc[4*r+1]; o[2]=acc[4*r+2]; o[3]=acc[4*r+3];
        __builtin_nontemporal_store(o, op+r);
      }
    }
  }
}

extern "C" void kernel_launch(void* const* d_in, const int* in_sizes, int n_in,
                              void* d_out, int out_size, void* d_ws, size_t ws_size,
                              hipStream_t stream){
  const float* x    = (const float*)d_in[0];
  const float* gpw  = (const float*)d_in[1];
  const float* jpw  = (const float*)d_in[2];
  const float* linw = (const float*)d_in[3];
  float* outp = (float*)d_out;

  float* wrp  = (float*)d_ws;          // 64*64*12 floats = 192 KB
  float* coef = wrp + 64*64*12;        // NQ*64 floats ≈ 68 KB

  int B = in_sizes[0] / (64*16);

  prep_wrp <<<192, 256, 0, stream>>>(linw, wrp);
  prep_coef<<<1,   64,  0, stream>>>(gpw, jpw, coef);
  main_k   <<<512, 512, 0, stream>>>(x, coef, wrp, outp, B);
}